// Round 11
// baseline (6334.623 us; speedup 1.0000x reference)
//
#include <hip/hip_runtime.h>
#include <stdint.h>

typedef unsigned int u32;
typedef unsigned short u16;
typedef unsigned long long u64;
typedef _Float16 f16;
typedef _Float16 h2_t __attribute__((ext_vector_type(2)));
typedef _Float16 f16x4 __attribute__((ext_vector_type(4)));
typedef _Float16 f16x8 __attribute__((ext_vector_type(8)));
typedef float f32x4 __attribute__((ext_vector_type(4)));
typedef float f32x16 __attribute__((ext_vector_type(16)));
typedef u32 u32x4 __attribute__((ext_vector_type(4)));

#define TT 512
#define NF 128
#define NTOT (256 * TT)

// ---- ws layout (bytes) ----
#define OFF_WA0   0u          // 786432 f16 = 1,572,864
#define OFF_WA1   1572864u    // 524288 f16 = 1,048,576
#define OFF_WAH   2621440u    // 131072 f16 =   262,144
#define OFF_GSUM  2883584u    // 128 f32 (+pad)
#define OFF_GSQ   2884096u    // 128 f32 (+pad)
#define OFF_CTR   2884608u    // 1024 u32 (32 counters, 128B apart) = 4096
#define OFF_GH    2888704u    // 4 bufs x 8 groups x 1024 u64 = 262,144
#define OFF_Y     3150848u    // 131072*128 f16 = 33,554,432

__device__ __forceinline__ float sigf(float x) { return 1.0f / (1.0f + __expf(-x)); }
__device__ __forceinline__ float tanh_fast(float x) { return 1.0f - 2.0f / (__expf(2.0f * x) + 1.0f); }

// ---------------- prep: identical weight packing to r10 (verified); zero stats/ctrs ----
__global__ void prep_kernel(const float* __restrict__ Wih0, const float* __restrict__ Whh0,
                            const float* __restrict__ Wih1, const float* __restrict__ Whh1,
                            const float* __restrict__ W1,
                            f16* __restrict__ WA0, f16* __restrict__ WA1, f16* __restrict__ WAH,
                            float* __restrict__ gz, u32* __restrict__ ctr) {
    int idx = blockIdx.x * 256 + threadIdx.x;
    const int n0 = 786432, n1 = 524288, n2 = 131072;
    if (idx < n0) {
        int u = idx >> 9, r9 = idx & 511;
        int lane = r9 >> 3, j = r9 & 7;
        int ks = u % 6; u /= 6;
        int wv = u & 7, w = u >> 3;
        int lr = lane & 31, h = lane >> 5;
        int r = ((lr >> 3) << 8) + 8 * w + (lr & 7);
        int seg = ks >> 1, sig = ks & 1;
        int c = 256 * seg + 32 * wv + 16 * sig + 8 * h + j;
        float v = (c < 512) ? Wih0[r * 512 + c] : Whh0[r * 256 + (c - 512)];
        WA0[idx] = (f16)v;
    } else if (idx < n0 + n1) {
        int i2 = idx - n0;
        int lane = (i2 >> 3) & 63, j = i2 & 7;
        int ks = (i2 >> 9) & 3, wv = (i2 >> 11) & 7, w = i2 >> 14;
        int lr = lane & 31, h = lane >> 5;
        int r = ((lr >> 3) << 8) + 8 * w + (lr & 7);
        int sig = ks & 1;
        int c = 32 * wv + 16 * sig + 8 * h + j;
        float v = (ks >> 1) ? Whh1[r * 256 + c] : Wih1[r * 256 + c];
        WA1[i2] = (f16)v;
    } else if (idx < n0 + n1 + n2) {
        int i2 = idx - n0 - n1;
        int u = i2 >> 9, r9 = i2 & 511;
        int lane = r9 >> 3, j = r9 & 7;
        int ks = u & 7, w = u >> 3;
        int m = lane & 15, hh = lane >> 4;
        int k = 32 * ks + 8 * hh + j;
        float v = (m < 4) ? W1[(4 * w + m) * 256 + k] : 0.f;
        WAH[i2] = (f16)v;
    } else if (idx < n0 + n1 + n2 + 256) {
        gz[idx - n0 - n1 - n2] = 0.f;     // gsum[128] + gsq[128]
    } else if (idx < n0 + n1 + n2 + 256 + 1024) {
        ctr[idx - n0 - n1 - n2 - 256] = 0u;
    }
}

#define MFMA32L(A, BP, C) (C) = __builtin_amdgcn_mfma_f32_32x32x16_f16( \
    __builtin_bit_cast(f16x8, (A)), __builtin_bit_cast(f16x8, *(const uint4*)(BP)), (C), 0, 0, 0)
#define MFMA32R(A, B, C) (C) = __builtin_amdgcn_mfma_f32_32x32x16_f16( \
    __builtin_bit_cast(f16x8, (A)), __builtin_bit_cast(f16x8, (B)), (C), 0, 0, 0)

// zz write, cohort row base ZB (0 = X rows 0-15, 16 = Y rows 16-31); lanes 16-31 duplicate
#define ZZWRC(ZB, C) do { if (n32 < 16) { \
    f32x4 v0_ = {(C)[0], (C)[1], (C)[2], (C)[3]};    *(f32x4*)&zz[wv][(ZB) + n32][4 * h32] = v0_; \
    f32x4 v1_ = {(C)[4], (C)[5], (C)[6], (C)[7]};    *(f32x4*)&zz[wv][(ZB) + n32][8 + 4 * h32] = v1_; \
    f32x4 v2_ = {(C)[8], (C)[9], (C)[10], (C)[11]};  *(f32x4*)&zz[wv][(ZB) + n32][16 + 4 * h32] = v2_; \
    f32x4 v3_ = {(C)[12], (C)[13], (C)[14], (C)[15]}; *(f32x4*)&zz[wv][(ZB) + n32][24 + 4 * h32] = v3_; } } while (0)

#define GATHER2(F0, F1, P0, P1) asm volatile( \
    "global_load_dwordx4 %0, %2, off sc0 sc1\n\t" \
    "global_load_dwordx4 %1, %3, off sc0 sc1\n\t" \
    "s_waitcnt vmcnt(0)" \
    : "=&v"(F0), "=&v"(F1) : "v"(P0), "v"(P1) : "memory")

#define GATHER4(F0, F1, F2, F3, P0, P1, P2, P3) asm volatile( \
    "global_load_dwordx4 %0, %4, off sc0 sc1\n\t" \
    "global_load_dwordx4 %1, %5, off sc0 sc1\n\t" \
    "global_load_dwordx4 %2, %6, off sc0 sc1\n\t" \
    "global_load_dwordx4 %3, %7, off sc0 sc1\n\t" \
    "s_waitcnt vmcnt(0)" \
    : "=&v"(F0), "=&v"(F1), "=&v"(F2), "=&v"(F3) \
    : "v"(P0), "v"(P1), "v"(P2), "v"(P3) : "memory")

#define PUBX4(PTR, DATA) asm volatile( \
    "global_store_dwordx4 %0, %1, off sc0 sc1" :: "v"(PTR), "v"(DATA) : "memory")

#define POLL(CTRP, TGT) do { int gu_ = 0; \
    while (__hip_atomic_load((CTRP), __ATOMIC_RELAXED, __HIP_MEMORY_SCOPE_AGENT) < (TGT) \
           && ++gu_ < 200000000) {} } while (0)

#define LWAIT(LF, TGT) do { int gu_ = 0; \
    while (__hip_atomic_load(&(LF), __ATOMIC_RELAXED, __HIP_MEMORY_SCOPE_WORKGROUP) < (TGT) \
           && ++gu_ < 200000000) {} } while (0)

// cell math + shfl-collapse + direct 16B publish. CBL = local batch 0-15, ZB = zz row base.
#define CELLP(BCS, CSTATE, SRC, ZB) do { \
    float z0 = BCS[cj], z1 = BCS[8 + cj], z2 = BCS[16 + cj], z3 = BCS[24 + cj]; \
    _Pragma("unroll") \
    for (int kw_ = 0; kw_ < 8; ++kw_) { \
        z0 += zz[kw_][(ZB) + cb][cj];      z1 += zz[kw_][(ZB) + cb][8 + cj]; \
        z2 += zz[kw_][(ZB) + cb][16 + cj]; z3 += zz[kw_][(ZB) + cb][24 + cj]; \
    } \
    float c_ = sigf(z1) * (CSTATE) + sigf(z0) * tanh_fast(z2); \
    (CSTATE) = c_; \
    f16 hf_ = (f16)(sigf(z3) * tanh_fast(c_)); \
    u32 hb_ = (u32)__builtin_bit_cast(u16, hf_); \
    u32 p01_ = hb_ | ((u32)__shfl_xor((int)hb_, 1, 64) << 16); \
    u32 p23_ = (u32)__shfl_xor((int)p01_, 2, 64); \
    u32 p45_ = (u32)__shfl_xor((int)p01_, 4, 64); \
    u32 p67_ = (u32)__shfl_xor((int)p23_, 4, 64); \
    if (cj == 0) { \
        u32x4 word_ = {p01_, p23_, p45_, p67_}; \
        PUBX4((void*)((SRC) + (cb * 64 + 2 * w)), word_); \
    } } while (0)

#define DRAIN() asm volatile("s_waitcnt vmcnt(0)" ::: "memory")

// head on one wave; XB = cohort Xh2 buffer, BB = cohort batch base (0 or 16)
#define HEADC(XB, BB, TIDX) do { \
    f32x4 C_ = {}; \
    _Pragma("unroll") \
    for (int ks_ = 0; ks_ < 8; ++ks_) \
        C_ = __builtin_amdgcn_mfma_f32_16x16x32_f16( \
            __builtin_bit_cast(f16x8, ah[ks_]), \
            __builtin_bit_cast(f16x8, \
                *(const uint4*)&XB[lane & 15][32 * ks_ + 8 * ((lane >> 4) & 3)]), \
            C_, 0, 0, 0); \
    if (lane < 16) { \
        float y0 = C_[0] + b1s[0], y1 = C_[1] + b1s[1]; \
        float y2 = C_[2] + b1s[2], y3 = C_[3] + b1s[3]; \
        ys0 += y0; yq0 += y0 * y0; ys1 += y1; yq1 += y1 * y1; \
        ys2 += y2; yq2 += y2 * y2; ys3 += y3; yq3 += y3 * y3; \
        f16x4 yp; yp[0] = (f16)y0; yp[1] = (f16)y1; yp[2] = (f16)y2; yp[3] = (f16)y3; \
        int b_ = (BB) + lane; \
        ((u64*)ybuf)[((size_t)(g * 32 + b_) * 512 + (TIDX)) * 32 + w] = __builtin_bit_cast(u64, yp); \
    } } while (0)

// ---------------- main: 8 groups x 32 WGs; two-cohort (16+16 batch) pipelined exchange ----
__global__ __launch_bounds__(512) void lstm_group_kernel(
    const float* __restrict__ audio, const float* __restrict__ s_rt,
    const uint4* __restrict__ WA0, const uint4* __restrict__ WA1, const uint4* __restrict__ WAH,
    const float* __restrict__ bih0, const float* __restrict__ bhh0,
    const float* __restrict__ bih1, const float* __restrict__ bhh1,
    const float* __restrict__ b1, u32* __restrict__ ctr, u64* __restrict__ gh,
    f16* __restrict__ ybuf, float* __restrict__ gsum, float* __restrict__ gsq)
{
    __shared__ __align__(16) f16 XaX[16][264], XaY[16][264];    // audio staging, per cohort
    __shared__ __align__(16) f16 Xh2X[16][264], Xh2Y[16][264];  // h2 staging (head), per cohort
    __shared__ float zz[8][32][36];                             // rows 0-15 = X, 16-31 = Y
    __shared__ float bc0s[32], bc1s[32], b1s[4];
    __shared__ u32 lflag[4];
    __shared__ float pad_[2700];                                // force 1 WG/CU

    const int tid = threadIdx.x;
    const int w = blockIdx.x >> 3;     // row-slice 0..31
    const int g = blockIdx.x & 7;      // group 0..7
    const int wv = tid >> 6;
    const int lane = tid & 63;
    const int n32 = lane & 31;
    const int h32 = (lane >> 5) & 1;
    const int cb = (tid & 127) >> 3;   // local batch for cell waves (4-5: X, 6-7: Y)
    const int cj = tid & 7;

    if (tid == 0) {
        volatile float* vp = pad_; vp[0] = 0.f;
        lflag[0] = lflag[1] = lflag[2] = lflag[3] = 0u;
    }

    u32* const ctrX1 = ctr + (g * 4 + 0) * 32;
    u32* const ctrX2 = ctr + (g * 4 + 1) * 32;
    u32* const ctrY1 = ctr + (g * 4 + 2) * 32;
    u32* const ctrY2 = ctr + (g * 4 + 3) * 32;
    u64* const srcX1 = gh + (size_t)(g * 4 + 0) * 1024;
    u64* const srcX2 = gh + (size_t)(g * 4 + 1) * 1024;
    u64* const srcY1 = gh + (size_t)(g * 4 + 2) * 1024;
    u64* const srcY2 = gh + (size_t)(g * 4 + 3) * 1024;
    const size_t gb = (size_t)(n32 & 15) * 64 + 8 * wv + 2 * h32;
    const float4* const a4 = (const float4*)audio;

    // ---- persistent A-fragments (identical to r10) ----
    uint4 a0[6], a1[4], ah[8] = {};
    #pragma unroll
    for (int ks = 0; ks < 6; ++ks) a0[ks] = WA0[((w * 8 + wv) * 6 + ks) * 64 + lane];
    #pragma unroll
    for (int ks = 0; ks < 4; ++ks) a1[ks] = WA1[((w * 8 + wv) * 4 + ks) * 64 + lane];
    if (wv < 2) {
        #pragma unroll
        for (int ks = 0; ks < 8; ++ks) ah[ks] = WAH[(w * 8 + ks) * 64 + lane];
    }
    if (tid < 32) {
        int r = ((tid >> 3) << 8) + 8 * w + (tid & 7);
        bc0s[tid] = bih0[r] + bhh0[r];
        bc1s[tid] = bih1[r] + bhh1[r];
    }
    if (tid < 4) b1s[tid] = b1[4 * w + tid];

    // ---- init: prev_out -> Xh2*, audio(0) -> Xa* ----
    for (int it = tid; it < 32 * 256; it += 512) {
        int b = it >> 8, c = it & 255;
        const float* sp = s_rt + ((size_t)(32 * g + b) * 16) * 256 + c;
        float s = 0.f;
        #pragma unroll
        for (int l = 0; l < 16; ++l) s += sp[l * 256];
        f16 po = (f16)(s * 0.0625f);
        f16 au = (f16)audio[((size_t)(32 * g + b) * 512) * 256 + c];
        if (b < 16) { Xh2X[b][c] = po; XaX[b][c] = au; }
        else        { Xh2Y[b - 16][c] = po; XaY[b - 16][c] = au; }
    }
    __syncthreads();

    u32x4 f20X = *(const u32x4*)&Xh2X[n32 & 15][32 * wv + 8 * h32];
    u32x4 f21X = *(const u32x4*)&Xh2X[n32 & 15][32 * wv + 16 + 8 * h32];
    u32x4 f20Y = *(const u32x4*)&Xh2Y[n32 & 15][32 * wv + 8 * h32];
    u32x4 f21Y = *(const u32x4*)&Xh2Y[n32 & 15][32 * wv + 16 + 8 * h32];
    u32x4 f10X = {0, 0, 0, 0}, f11X = {0, 0, 0, 0};
    u32x4 f10Y = {0, 0, 0, 0}, f11Y = {0, 0, 0, 0};
    float4 avX[8], avY[8];

    float c1 = 0.f, c2 = 0.f;   // cell states (waves4-5: X, waves6-7: Y)
    float ys0 = 0, ys1 = 0, ys2 = 0, ys3 = 0, yq0 = 0, yq1 = 0, yq2 = 0, yq3 = 0;

    for (int t = 0; t < TT; ++t) {
        const u32 T = (u32)(t + 1);
        // ============ slot0: gather h2X(t-1), h1Y(t-1); F1-X(t); D-Y(t-1) ============
        if (t > 0) {
            GATHER4(f20X, f21X, f10Y, f11Y,
                    (const void*)(srcX2 + gb), (const void*)(srcX2 + gb + 4),
                    (const void*)(srcY1 + gb), (const void*)(srcY1 + gb + 4));
            if (n32 < 16) {
                *(u32x4*)&Xh2X[n32][32 * wv + 8 * h32] = f20X;
                *(u32x4*)&Xh2X[n32][32 * wv + 16 + 8 * h32] = f21X;
            }
        }
        if ((wv == 2 || wv == 3) && t + 1 < TT) {
            #pragma unroll
            for (int s = 0; s < 8; ++s)
                avX[s] = a4[(size_t)(32 * g + (wv - 2) * 8 + s) * 32768 + (size_t)(t + 1) * 64 + lane];
        }
        {
            f32x16 aXF = {};    // L0 gates X(t): [h2X(t-1)|prev_out, audio(t), h1X(t-1)]
            MFMA32R(a0[0], f20X, aXF); MFMA32R(a0[1], f21X, aXF);
            MFMA32L(a0[2], &XaX[n32 & 15][32 * wv + 8 * h32], aXF);
            MFMA32L(a0[3], &XaX[n32 & 15][32 * wv + 16 + 8 * h32], aXF);
            MFMA32R(a0[4], f10X, aXF); MFMA32R(a0[5], f11X, aXF);
            ZZWRC(0, aXF);
            f32x16 aYD = {};    // L1 gates Y(t-1): [h1Y(t-1), h2Y(t-2)]
            if (t > 0) {
                MFMA32R(a1[0], f10Y, aYD); MFMA32R(a1[1], f11Y, aYD);
                if (t > 1) { MFMA32R(a1[2], f20Y, aYD); MFMA32R(a1[3], f21Y, aYD); }
            }
            ZZWRC(16, aYD);
        }
        __syncthreads();   // #1
        // ============ slot1: cells X-L0 (pub X1, T) + Y-L1 (pub Y2, t); headX; polls ============
        if (wv == 4 || wv == 5) {
            CELLP(bc0s, c1, srcX1, 0);
            DRAIN();
            if (lane == 0) __hip_atomic_fetch_add(&lflag[0], 1u, __ATOMIC_RELAXED, __HIP_MEMORY_SCOPE_WORKGROUP);
            if (tid == 256) {
                LWAIT(lflag[0], 2u * T);
                __hip_atomic_fetch_add(ctrX1, 1u, __ATOMIC_RELAXED, __HIP_MEMORY_SCOPE_AGENT);
            }
        } else if (wv >= 6) {
            if (t > 0) {
                CELLP(bc1s, c2, srcY2, 16);
                DRAIN();
                if (lane == 0) __hip_atomic_fetch_add(&lflag[1], 1u, __ATOMIC_RELAXED, __HIP_MEMORY_SCOPE_WORKGROUP);
                if (tid == 384) {
                    LWAIT(lflag[1], 2u * (u32)t);
                    __hip_atomic_fetch_add(ctrY2, 1u, __ATOMIC_RELAXED, __HIP_MEMORY_SCOPE_AGENT);
                }
            }
        } else if (wv == 0) {
            if (t > 0) HEADC(Xh2X, 0, t - 1);
            if (lane == 0) POLL(ctrX1, 32u * T);
        } else if (wv == 1) {
            if (lane == 0) POLL(ctrY2, 32u * (u32)t);
        } else {  // wv 2,3: pack XaY(t)
            if (t > 0) {
                #pragma unroll
                for (int s = 0; s < 8; ++s) {
                    h2_t p0_; p0_.x = (f16)avY[s].x; p0_.y = (f16)avY[s].y;
                    h2_t p1_; p1_.x = (f16)avY[s].z; p1_.y = (f16)avY[s].w;
                    uint2 pv_; pv_.x = __builtin_bit_cast(u32, p0_); pv_.y = __builtin_bit_cast(u32, p1_);
                    *(uint2*)&XaY[(wv - 2) * 8 + s][4 * lane] = pv_;
                }
            }
        }
        __syncthreads();   // #2
        // ============ slot2: gather h1X(t), h2Y(t-1); D-X(t); F1-Y(t); stage Xh2Y ============
        if (t > 0) {
            GATHER4(f10X, f11X, f20Y, f21Y,
                    (const void*)(srcX1 + gb), (const void*)(srcX1 + gb + 4),
                    (const void*)(srcY2 + gb), (const void*)(srcY2 + gb + 4));
            if (n32 < 16) {
                *(u32x4*)&Xh2Y[n32][32 * wv + 8 * h32] = f20Y;
                *(u32x4*)&Xh2Y[n32][32 * wv + 16 + 8 * h32] = f21Y;
            }
        } else {
            GATHER2(f10X, f11X, (const void*)(srcX1 + gb), (const void*)(srcX1 + gb + 4));
        }
        if ((wv == 2 || wv == 3) && t + 1 < TT) {
            #pragma unroll
            for (int s = 0; s < 8; ++s)
                avY[s] = a4[(size_t)(32 * g + 16 + (wv - 2) * 8 + s) * 32768 + (size_t)(t + 1) * 64 + lane];
        }
        {
            f32x16 aXD = {};    // L1 gates X(t): [h1X(t), h2X(t-1)]
            MFMA32R(a1[0], f10X, aXD); MFMA32R(a1[1], f11X, aXD);
            if (t > 0) { MFMA32R(a1[2], f20X, aXD); MFMA32R(a1[3], f21X, aXD); }
            ZZWRC(0, aXD);
            f32x16 aYF = {};    // L0 gates Y(t): [h2Y(t-1)|prev_out, audio(t), h1Y(t-1)]
            MFMA32R(a0[0], f20Y, aYF); MFMA32R(a0[1], f21Y, aYF);
            MFMA32L(a0[2], &XaY[n32 & 15][32 * wv + 8 * h32], aYF);
            MFMA32L(a0[3], &XaY[n32 & 15][32 * wv + 16 + 8 * h32], aYF);
            MFMA32R(a0[4], f10Y, aYF); MFMA32R(a0[5], f11Y, aYF);
            ZZWRC(16, aYF);
        }
        __syncthreads();   // #3
        // ============ slot3: cells X-L1 (pub X2, T) + Y-L0 (pub Y1, T); headY; polls ============
        if (wv == 4 || wv == 5) {
            CELLP(bc1s, c2, srcX2, 0);
            DRAIN();
            if (lane == 0) __hip_atomic_fetch_add(&lflag[2], 1u, __ATOMIC_RELAXED, __HIP_MEMORY_SCOPE_WORKGROUP);
            if (tid == 256) {
                LWAIT(lflag[2], 2u * T);
                __hip_atomic_fetch_add(ctrX2, 1u, __ATOMIC_RELAXED, __HIP_MEMORY_SCOPE_AGENT);
            }
        } else if (wv >= 6) {
            CELLP(bc0s, c1, srcY1, 16);
            DRAIN();
            if (lane == 0) __hip_atomic_fetch_add(&lflag[3], 1u, __ATOMIC_RELAXED, __HIP_MEMORY_SCOPE_WORKGROUP);
            if (tid == 384) {
                LWAIT(lflag[3], 2u * T);
                __hip_atomic_fetch_add(ctrY1, 1u, __ATOMIC_RELAXED, __HIP_MEMORY_SCOPE_AGENT);
            }
        } else if (wv == 0) {
            if (lane == 0) POLL(ctrX2, 32u * T);
        } else if (wv == 1) {
            if (t > 0) HEADC(Xh2Y, 16, t - 1);
            if (lane == 0) POLL(ctrY1, 32u * T);
        } else {  // wv 2,3: pack XaX(t+1)
            if (t + 1 < TT) {
                #pragma unroll
                for (int s = 0; s < 8; ++s) {
                    h2_t p0_; p0_.x = (f16)avX[s].x; p0_.y = (f16)avX[s].y;
                    h2_t p1_; p1_.x = (f16)avX[s].z; p1_.y = (f16)avX[s].w;
                    uint2 pv_; pv_.x = __builtin_bit_cast(u32, p0_); pv_.y = __builtin_bit_cast(u32, p1_);
                    *(uint2*)&XaX[(wv - 2) * 8 + s][4 * lane] = pv_;
                }
            }
        }
        __syncthreads();   // #4
    }
    // ================= epilogue =================
    // E0: gather h2X(TT-1), h1Y(TT-1); D-Y(TT-1)
    GATHER4(f20X, f21X, f10Y, f11Y,
            (const void*)(srcX2 + gb), (const void*)(srcX2 + gb + 4),
            (const void*)(srcY1 + gb), (const void*)(srcY1 + gb + 4));
    if (n32 < 16) {
        *(u32x4*)&Xh2X[n32][32 * wv + 8 * h32] = f20X;
        *(u32x4*)&Xh2X[n32][32 * wv + 16 + 8 * h32] = f21X;
    }
    {
        f32x16 aYD = {};
        MFMA32R(a1[0], f10Y, aYD); MFMA32R(a1[1], f11Y, aYD);
        MFMA32R(a1[2], f20Y, aYD); MFMA32R(a1[3], f21Y, aYD);
        ZZWRC(16, aYD);
    }
    __syncthreads();
    // E1: cells Y-L1 -> pub Y2 (T = TT); headX(TT-1); wave1 polls
    if (wv >= 6) {
        CELLP(bc1s, c2, srcY2, 16);
        DRAIN();
        if (lane == 0) __hip_atomic_fetch_add(&lflag[1], 1u, __ATOMIC_RELAXED, __HIP_MEMORY_SCOPE_WORKGROUP);
        if (tid == 384) {
            LWAIT(lflag[1], 2u * (u32)TT);
            __hip_atomic_fetch_add(ctrY2, 1u, __ATOMIC_RELAXED, __HIP_MEMORY_SCOPE_AGENT);
        }
    } else if (wv == 0) {
        HEADC(Xh2X, 0, TT - 1);
    } else if (wv == 1) {
        if (lane == 0) POLL(ctrY2, 32u * (u32)TT);
    }
    __syncthreads();
    // E2: gather h2Y(TT-1) -> Xh2Y
    GATHER2(f20Y, f21Y, (const void*)(srcY2 + gb), (const void*)(srcY2 + gb + 4));
    if (n32 < 16) {
        *(u32x4*)&Xh2Y[n32][32 * wv + 8 * h32] = f20Y;
        *(u32x4*)&Xh2Y[n32][32 * wv + 16 + 8 * h32] = f21Y;
    }
    __syncthreads();
    // E3: headY(TT-1); BN stats
    if (wv == 1) HEADC(Xh2Y, 16, TT - 1);
    if (wv < 2 && lane < 16) {
        #pragma unroll
        for (int m = 8; m >= 1; m >>= 1) {
            ys0 += __shfl_xor(ys0, m, 64); ys1 += __shfl_xor(ys1, m, 64);
            ys2 += __shfl_xor(ys2, m, 64); ys3 += __shfl_xor(ys3, m, 64);
            yq0 += __shfl_xor(yq0, m, 64); yq1 += __shfl_xor(yq1, m, 64);
            yq2 += __shfl_xor(yq2, m, 64); yq3 += __shfl_xor(yq3, m, 64);
        }
        if (lane == 0) {
            atomicAdd(&gsum[4 * w + 0], ys0); atomicAdd(&gsum[4 * w + 1], ys1);
            atomicAdd(&gsum[4 * w + 2], ys2); atomicAdd(&gsum[4 * w + 3], ys3);
            atomicAdd(&gsq[4 * w + 0], yq0); atomicAdd(&gsq[4 * w + 1], yq1);
            atomicAdd(&gsq[4 * w + 2], yq2); atomicAdd(&gsq[4 * w + 3], yq3);
        }
    }
}

// ---------------- final head: BN(train) + ReLU + Linear(128->6) ----------------
__global__ __launch_bounds__(256) void head_kernel(
    const f16* __restrict__ ybuf, const float* __restrict__ gsum, const float* __restrict__ gsq,
    const float* __restrict__ gamma, const float* __restrict__ beta,
    const float* __restrict__ W2, const float* __restrict__ b2,
    float* __restrict__ out)
{
    __shared__ float sc[NF], sh[NF], W2s[6 * NF], b2s[6];
    const int tid = threadIdx.x;
    if (tid < NF) {
        const float invN = 1.f / (float)NTOT;
        float mu = gsum[tid] * invN;
        float var = gsq[tid] * invN - mu * mu;
        float iv = rsqrtf(var + 1e-5f);
        float s = gamma[tid] * iv;
        sc[tid] = s;
        sh[tid] = beta[tid] - mu * s;
    }
    for (int i = tid; i < 6 * NF; i += 256) W2s[i] = W2[i];
    if (tid < 6) b2s[tid] = b2[tid];
    __syncthreads();

    size_t n = (size_t)blockIdx.x * 256 + tid;
    const h2_t* yr = (const h2_t*)(ybuf + n * NF);
    float a0 = b2s[0], a1 = b2s[1], a2 = b2s[2], a3 = b2s[3], a4 = b2s[4], a5 = b2s[5];
    #pragma unroll 8
    for (int p = 0; p < 64; ++p) {
        h2_t v = yr[p];
        int f0 = 2 * p, f1 = 2 * p + 1;
        float v0 = fmaxf(fmaf((float)v.x, sc[f0], sh[f0]), 0.f);
        float v1 = fmaxf(fmaf((float)v.y, sc[f1], sh[f1]), 0.f);
        a0 = fmaf(v0, W2s[0 * NF + f0], a0); a0 = fmaf(v1, W2s[0 * NF + f1], a0);
        a1 = fmaf(v0, W2s[1 * NF + f0], a1); a1 = fmaf(v1, W2s[1 * NF + f1], a1);
        a2 = fmaf(v0, W2s[2 * NF + f0], a2); a2 = fmaf(v1, W2s[2 * NF + f1], a2);
        a3 = fmaf(v0, W2s[3 * NF + f0], a3); a3 = fmaf(v1, W2s[3 * NF + f1], a3);
        a4 = fmaf(v0, W2s[4 * NF + f0], a4); a4 = fmaf(v1, W2s[4 * NF + f1], a4);
        a5 = fmaf(v0, W2s[5 * NF + f0], a5); a5 = fmaf(v1, W2s[5 * NF + f1], a5);
    }
    float* op = out + n * 6;
    op[0] = a0; op[1] = a1; op[2] = a2; op[3] = a3; op[4] = a4; op[5] = a5;
}

extern "C" void kernel_launch(void* const* d_in, const int* in_sizes, int n_in,
                              void* d_out, int out_size, void* d_ws, size_t ws_size,
                              hipStream_t stream) {
    const float* audio = (const float*)d_in[1];
    const float* s_rt  = (const float*)d_in[2];
    const float* Wih0  = (const float*)d_in[3];
    const float* Whh0  = (const float*)d_in[4];
    const float* bih0  = (const float*)d_in[5];
    const float* bhh0  = (const float*)d_in[6];
    const float* Wih1  = (const float*)d_in[7];
    const float* Whh1  = (const float*)d_in[8];
    const float* bih1  = (const float*)d_in[9];
    const float* bhh1  = (const float*)d_in[10];
    const float* W1    = (const float*)d_in[11];
    const float* b1    = (const float*)d_in[12];
    const float* gamma = (const float*)d_in[13];
    const float* beta  = (const float*)d_in[14];
    const float* W2    = (const float*)d_in[15];
    const float* b2    = (const float*)d_in[16];

    char* ws = (char*)d_ws;
    f16* WA0    = (f16*)(ws + OFF_WA0);
    f16* WA1    = (f16*)(ws + OFF_WA1);
    f16* WAH    = (f16*)(ws + OFF_WAH);
    float* gsum = (float*)(ws + OFF_GSUM);
    float* gsq  = (float*)(ws + OFF_GSQ);
    u32* ctrp   = (u32*)(ws + OFF_CTR);
    u64* ghp    = (u64*)(ws + OFF_GH);
    f16* ybuf   = (f16*)(ws + OFF_Y);
    float* out  = (float*)d_out;

    // prep: 786432 + 524288 + 131072 + 256 + 1024 = 1,443,072 = 5637 * 256
    prep_kernel<<<5637, 256, 0, stream>>>(Wih0, Whh0, Wih1, Whh1, W1,
                                          WA0, WA1, WAH, gsum, ctrp);

    lstm_group_kernel<<<256, 512, 0, stream>>>(audio, s_rt,
                                               (const uint4*)WA0, (const uint4*)WA1, (const uint4*)WAH,
                                               bih0, bhh0, bih1, bhh1, b1, ctrp, ghp,
                                               ybuf, gsum, gsq);

    head_kernel<<<NTOT / 256, 256, 0, stream>>>(ybuf, gsum, gsq, gamma, beta, W2, b2, out);
}

// Round 12
// 4381.284 us; speedup vs baseline: 1.4458x; 1.4458x over previous
//
#include <hip/hip_runtime.h>
#include <stdint.h>

typedef unsigned int u32;
typedef unsigned short u16;
typedef unsigned long long u64;
typedef _Float16 f16;
typedef _Float16 h2_t __attribute__((ext_vector_type(2)));
typedef _Float16 f16x4 __attribute__((ext_vector_type(4)));
typedef _Float16 f16x8 __attribute__((ext_vector_type(8)));
typedef float f32x4 __attribute__((ext_vector_type(4)));
typedef float f32x16 __attribute__((ext_vector_type(16)));
typedef u32 u32x4 __attribute__((ext_vector_type(4)));

#define TT 512
#define NF 128
#define NTOT (256 * TT)

// ---- ws layout (bytes) ----
#define OFF_WA0   0u          // 786432 f16 = 1,572,864
#define OFF_WA1   1572864u    // 524288 f16 = 1,048,576
#define OFF_WAH   2621440u    // 131072 f16 =   262,144
#define OFF_GSUM  2883584u    // 128 f32 (+pad)
#define OFF_GSQ   2884096u    // 128 f32 (+pad)
#define OFF_GH1   2884608u    // 8 groups * 8192 tagged-u32 = 262,144
#define OFF_GH2   3146752u    // 262,144
#define OFF_Y     3408896u    // 131072*128 f16 = 33,554,432

__device__ __forceinline__ float sigf(float x) { return 1.0f / (1.0f + __expf(-x)); }
__device__ __forceinline__ float tanh_fast(float x) { return 1.0f - 2.0f / (__expf(2.0f * x) + 1.0f); }

// ---------------- prep: pack weights into per-wave MFMA A-fragments (same as r10) --------
__global__ void prep_kernel(const float* __restrict__ Wih0, const float* __restrict__ Whh0,
                            const float* __restrict__ Wih1, const float* __restrict__ Whh1,
                            const float* __restrict__ W1,
                            f16* __restrict__ WA0, f16* __restrict__ WA1, f16* __restrict__ WAH,
                            float* __restrict__ gz, u32* __restrict__ ghz) {
    int idx = blockIdx.x * 256 + threadIdx.x;
    const int n0 = 786432, n1 = 524288, n2 = 131072;
    if (idx < n0) {
        int u = idx >> 9, r9 = idx & 511;
        int lane = r9 >> 3, j = r9 & 7;
        int ks = u % 6; u /= 6;
        int wv = u & 7, w = u >> 3;
        int lr = lane & 31, h = lane >> 5;
        int r = ((lr >> 3) << 8) + 8 * w + (lr & 7);
        int seg = ks >> 1, sig = ks & 1;
        int c = 256 * seg + 32 * wv + 16 * sig + 8 * h + j;
        float v = (c < 512) ? Wih0[r * 512 + c] : Whh0[r * 256 + (c - 512)];
        WA0[idx] = (f16)v;
    } else if (idx < n0 + n1) {
        int i2 = idx - n0;
        int lane = (i2 >> 3) & 63, j = i2 & 7;
        int ks = (i2 >> 9) & 3, wv = (i2 >> 11) & 7, w = i2 >> 14;
        int lr = lane & 31, h = lane >> 5;
        int r = ((lr >> 3) << 8) + 8 * w + (lr & 7);
        int sig = ks & 1;
        int c = 32 * wv + 16 * sig + 8 * h + j;
        float v = (ks >> 1) ? Whh1[r * 256 + c] : Wih1[r * 256 + c];
        WA1[i2] = (f16)v;
    } else if (idx < n0 + n1 + n2) {
        int i2 = idx - n0 - n1;
        int u = i2 >> 9, r9 = i2 & 511;
        int lane = r9 >> 3, j = r9 & 7;
        int ks = u & 7, w = u >> 3;
        int m = lane & 15, hh = lane >> 4;
        int k = 32 * ks + 8 * hh + j;
        float v = (m < 4) ? W1[(4 * w + m) * 256 + k] : 0.f;
        WAH[i2] = (f16)v;
    } else if (idx < n0 + n1 + n2 + 256) {
        gz[idx - n0 - n1 - n2] = 0.f;                 // gsum[128] + gsq[128]
    } else if (idx < n0 + n1 + n2 + 256 + 131072) {
        ghz[idx - n0 - n1 - n2 - 256] = 0u;           // gh1 + gh2 tags cleared
    }
}

#define MFMA32L(A, BP, C) (C) = __builtin_amdgcn_mfma_f32_32x32x16_f16( \
    __builtin_bit_cast(f16x8, (A)), __builtin_bit_cast(f16x8, *(const uint4*)(BP)), (C), 0, 0, 0)
#define MFMA32R(A, B, C) (C) = __builtin_amdgcn_mfma_f32_32x32x16_f16( \
    __builtin_bit_cast(f16x8, (A)), __builtin_bit_cast(f16x8, (B)), (C), 0, 0, 0)

#define ZZWR(KW, C) do { \
    f32x4 v0_ = {(C)[0], (C)[1], (C)[2], (C)[3]};    *(f32x4*)&zz[KW][n32][4 * h32] = v0_; \
    f32x4 v1_ = {(C)[4], (C)[5], (C)[6], (C)[7]};    *(f32x4*)&zz[KW][n32][8 + 4 * h32] = v1_; \
    f32x4 v2_ = {(C)[8], (C)[9], (C)[10], (C)[11]};  *(f32x4*)&zz[KW][n32][16 + 4 * h32] = v2_; \
    f32x4 v3_ = {(C)[12], (C)[13], (C)[14], (C)[15]}; *(f32x4*)&zz[KW][n32][24 + 4 * h32] = v3_; } while (0)

#define PUBX4(PTR, DATA) asm volatile( \
    "global_store_dwordx4 %0, %1, off sc0 sc1" :: "v"(PTR), "v"(DATA) : "memory")

#define LOAD4T(W0, W1, W2, W3, B) asm volatile( \
    "global_load_dwordx4 %0, %4, off sc0 sc1\n\t" \
    "global_load_dwordx4 %1, %5, off sc0 sc1\n\t" \
    "global_load_dwordx4 %2, %6, off sc0 sc1\n\t" \
    "global_load_dwordx4 %3, %7, off sc0 sc1\n\t" \
    "s_waitcnt vmcnt(0)" \
    : "=&v"(W0), "=&v"(W1), "=&v"(W2), "=&v"(W3) \
    : "v"(B), "v"((B) + 4), "v"((B) + 16), "v"((B) + 20) : "memory")

// tagged gather: poll own 16 words until every tag == T, then unpack to 2 fragments
#define TGATHER(F0, F1, BASE, T) do { \
    const u32* b_ = (BASE); \
    u32x4 w0_, w1_, w2_, w3_; \
    LOAD4T(w0_, w1_, w2_, w3_, b_); \
    int gu_ = 0; \
    while (true) { \
        u32 st_ = ((w0_.x >> 16) ^ (T)) | ((w0_.y >> 16) ^ (T)) \
                | ((w0_.z >> 16) ^ (T)) | ((w0_.w >> 16) ^ (T)) \
                | ((w1_.x >> 16) ^ (T)) | ((w1_.y >> 16) ^ (T)) \
                | ((w1_.z >> 16) ^ (T)) | ((w1_.w >> 16) ^ (T)) \
                | ((w2_.x >> 16) ^ (T)) | ((w2_.y >> 16) ^ (T)) \
                | ((w2_.z >> 16) ^ (T)) | ((w2_.w >> 16) ^ (T)) \
                | ((w3_.x >> 16) ^ (T)) | ((w3_.y >> 16) ^ (T)) \
                | ((w3_.z >> 16) ^ (T)) | ((w3_.w >> 16) ^ (T)); \
        if (st_ == 0 || ++gu_ > 200000) break; \
        __builtin_amdgcn_s_sleep(1); \
        LOAD4T(w0_, w1_, w2_, w3_, b_); \
    } \
    (F0).x = (w0_.x & 0xffffu) | (w0_.y << 16); \
    (F0).y = (w0_.z & 0xffffu) | (w0_.w << 16); \
    (F0).z = (w1_.x & 0xffffu) | (w1_.y << 16); \
    (F0).w = (w1_.z & 0xffffu) | (w1_.w << 16); \
    (F1).x = (w2_.x & 0xffffu) | (w2_.y << 16); \
    (F1).y = (w2_.z & 0xffffu) | (w2_.w << 16); \
    (F1).z = (w3_.x & 0xffffu) | (w3_.y << 16); \
    (F1).w = (w3_.z & 0xffffu) | (w3_.w << 16); \
} while (0)

#define HEAD_BODY(TIDX) do { \
    f32x4 C_ = {}; \
    _Pragma("unroll") \
    for (int ks_ = 0; ks_ < 8; ++ks_) \
        C_ = __builtin_amdgcn_mfma_f32_16x16x32_f16( \
            __builtin_bit_cast(f16x8, ah[ks_]), \
            __builtin_bit_cast(f16x8, \
                *(const uint4*)&Xh2[wv * 16 + (lane & 15)][32 * ks_ + 8 * ((lane >> 4) & 3)]), \
            C_, 0, 0, 0); \
    if (lane < 16) { \
        float y0 = C_[0] + b1s[0], y1 = C_[1] + b1s[1]; \
        float y2 = C_[2] + b1s[2], y3 = C_[3] + b1s[3]; \
        ys0 += y0; yq0 += y0 * y0; ys1 += y1; yq1 += y1 * y1; \
        ys2 += y2; yq2 += y2 * y2; ys3 += y3; yq3 += y3 * y3; \
        f16x4 yp; yp[0] = (f16)y0; yp[1] = (f16)y1; yp[2] = (f16)y2; yp[3] = (f16)y3; \
        int b_ = wv * 16 + lane; \
        ((u64*)ybuf)[((size_t)(g * 32 + b_) * 512 + (TIDX)) * 32 + w] = __builtin_bit_cast(u64, yp); \
    } } while (0)

// cell math + per-dim tagged publish (dim = 8w+cj; word = 4 tagged dims; no drain needed)
#define CELLPT(BCS, CSTATE, SRC, TG) do { \
    float z0 = BCS[cj], z1 = BCS[8 + cj], z2 = BCS[16 + cj], z3 = BCS[24 + cj]; \
    _Pragma("unroll") \
    for (int kw_ = 0; kw_ < 8; ++kw_) { \
        z0 += zz[kw_][cb][cj];      z1 += zz[kw_][cb][8 + cj]; \
        z2 += zz[kw_][cb][16 + cj]; z3 += zz[kw_][cb][24 + cj]; \
    } \
    float c_ = sigf(z1) * (CSTATE) + sigf(z0) * tanh_fast(z2); \
    (CSTATE) = c_; \
    f16 hf_ = (f16)(sigf(z3) * tanh_fast(c_)); \
    u32 tw_ = ((TG) << 16) | (u32)__builtin_bit_cast(u16, hf_); \
    u32 t1_ = (u32)__shfl_xor((int)tw_, 1, 64); \
    u32 t2_ = (u32)__shfl_xor((int)tw_, 2, 64); \
    u32 t3_ = (u32)__shfl_xor((int)tw_, 3, 64); \
    if ((cj & 3) == 0) { \
        u32x4 word_ = {tw_, t1_, t2_, t3_}; \
        PUBX4((void*)((SRC) + (cb * 256 + 8 * w + cj)), word_); \
    } } while (0)

// ---------------- main: 8 groups x 32 row-slice WGs; tag-dataflow exchange ----
__global__ __launch_bounds__(512) void lstm_group_kernel(
    const float* __restrict__ audio, const float* __restrict__ s_rt,
    const uint4* __restrict__ WA0, const uint4* __restrict__ WA1, const uint4* __restrict__ WAH,
    const float* __restrict__ bih0, const float* __restrict__ bhh0,
    const float* __restrict__ bih1, const float* __restrict__ bhh1,
    const float* __restrict__ b1,
    u32* __restrict__ gh1, u32* __restrict__ gh2,
    f16* __restrict__ ybuf, float* __restrict__ gsum, float* __restrict__ gsq)
{
    __shared__ __align__(16) f16 Xa[32][264];   // audio(t+1) staging       16,896 B
    __shared__ __align__(16) f16 Xh2[32][264];  // h2(t) staged (head)      16,896 B
    __shared__ float zz[8][32][36];             // per-wave partials        36,864 B
    __shared__ float bc0s[32], bc1s[32], b1s[4];
    __shared__ float pad_[2700];                // force 1 WG/CU (>80 KiB total)

    const int tid = threadIdx.x;
    const int w = blockIdx.x >> 3;     // row-slice 0..31
    const int g = blockIdx.x & 7;      // group 0..7
    const int wv = tid >> 6;
    const int lane = tid & 63;
    const int n32 = lane & 31;
    const int h32 = (lane >> 5) & 1;
    const int ct = tid - 256;          // cell threads = waves 4..7
    const int cb = ct >> 3, cj = ct & 7;
    const int bg = tid >> 6, aq = tid & 63;    // audio mapping (waves 0..3)

    if (tid == 0) { volatile float* vp = pad_; vp[0] = 0.f; }

    u32* const src1 = gh1 + (size_t)g * 8192;
    u32* const src2 = gh2 + (size_t)g * 8192;
    const u32* const gb1 = src1 + (size_t)n32 * 256 + 32 * wv + 8 * h32;
    const u32* const gb2 = src2 + (size_t)n32 * 256 + 32 * wv + 8 * h32;
    const float4* const a4 = (const float4*)audio;

    // ---- persistent A-fragments ----
    uint4 a0[6], a1[4], ah[8] = {};
    #pragma unroll
    for (int ks = 0; ks < 6; ++ks) a0[ks] = WA0[((w * 8 + wv) * 6 + ks) * 64 + lane];
    #pragma unroll
    for (int ks = 0; ks < 4; ++ks) a1[ks] = WA1[((w * 8 + wv) * 4 + ks) * 64 + lane];
    if (wv < 2) {
        #pragma unroll
        for (int ks = 0; ks < 8; ++ks) ah[ks] = WAH[(w * 8 + ks) * 64 + lane];
    }
    if (tid < 32) {
        int r = ((tid >> 3) << 8) + 8 * w + (tid & 7);
        bc0s[tid] = bih0[r] + bhh0[r];
        bc1s[tid] = bih1[r] + bhh1[r];
    }
    if (tid < 4) b1s[tid] = b1[4 * w + tid];

    // ---- init: prev_out -> Xh2, audio(0) -> Xa ----
    for (int it = tid; it < 32 * 256; it += 512) {
        int b = it >> 8, c = it & 255;
        const float* sp = s_rt + ((size_t)(32 * g + b) * 16) * 256 + c;
        float s = 0.f;
        #pragma unroll
        for (int l = 0; l < 16; ++l) s += sp[l * 256];
        Xh2[b][c] = (f16)(s * 0.0625f);
        Xa[b][c] = (f16)audio[((size_t)(32 * g + b) * 512) * 256 + c];
    }
    // prologue: audio(1) into registers (waves 0..3, 8 batches each)
    float4 av[8];
    if (wv < 4) {
        #pragma unroll
        for (int s = 0; s < 8; ++s)
            av[s] = a4[(size_t)(32 * g + 8 * bg + s) * 32768 + 64 + aq];
    }
    __syncthreads();

    u32x4 f20 = *(const u32x4*)&Xh2[n32][32 * wv + 8 * h32];
    u32x4 f21 = *(const u32x4*)&Xh2[n32][32 * wv + 16 + 8 * h32];
    u32x4 f10 = {0, 0, 0, 0}, f11 = {0, 0, 0, 0};
    f32x16 aAcc = {};
    MFMA32L(a0[2], &Xa[n32][32 * wv + 8 * h32], aAcc);
    MFMA32L(a0[3], &Xa[n32][32 * wv + 16 + 8 * h32], aAcc);

    float c1 = 0.f, c2 = 0.f;
    float ys0 = 0, ys1 = 0, ys2 = 0, ys3 = 0, yq0 = 0, yq1 = 0, yq2 = 0, yq3 = 0;

    for (int t = 0; t < TT; ++t) {
        const u32 T = (u32)(t + 1);
        // ---- A-finish: h2(t-1)/prev_out part ----
        MFMA32R(a0[0], f20, aAcc);
        MFMA32R(a0[1], f21, aAcc);
        ZZWR(wv, aAcc);
        __syncthreads();   // #1 (zz-A complete)

        // ---- window1: cells L0 publish tagged h1; others Dacc h2-part + head + pack Xa ----
        f32x16 Dacc = {};
        if (wv >= 4) {
            CELLPT(bc0s, c1, src1, T);
            if (t > 0) { MFMA32R(a1[2], f20, Dacc); MFMA32R(a1[3], f21, Dacc); }
        } else {
            if (t > 0) { MFMA32R(a1[2], f20, Dacc); MFMA32R(a1[3], f21, Dacc); }
            if (wv < 2 && t > 0) HEAD_BODY(t - 1);
            if (t + 1 < TT) {
                #pragma unroll
                for (int s = 0; s < 8; ++s) {
                    h2_t p0_; p0_.x = (f16)av[s].x; p0_.y = (f16)av[s].y;
                    h2_t p1_; p1_.x = (f16)av[s].z; p1_.y = (f16)av[s].w;
                    uint2 pv_;
                    pv_.x = __builtin_bit_cast(u32, p0_);
                    pv_.y = __builtin_bit_cast(u32, p1_);
                    *(uint2*)&Xa[8 * bg + s][4 * aq] = pv_;
                }
            }
        }
        __syncthreads();   // #2 (zz-A reads done; Xa(t+1) staged)

        // ---- gather h1(t) via tags -> B-fragments; D: L1 h1-part ----
        TGATHER(f10, f11, gb1, T);
        MFMA32R(a1[0], f10, Dacc);
        MFMA32R(a1[1], f11, Dacc);
        ZZWR(wv, Dacc);
        __syncthreads();   // #3 (zz-D complete)

        // ---- window2: cells L1 publish tagged h2; all waves A-pre for t+1 ----
        aAcc = (f32x16){};
        if (wv >= 4) {
            CELLPT(bc1s, c2, src2, T);
            if (t + 1 < TT) {
                MFMA32L(a0[2], &Xa[n32][32 * wv + 8 * h32], aAcc);
                MFMA32L(a0[3], &Xa[n32][32 * wv + 16 + 8 * h32], aAcc);
                MFMA32R(a0[4], f10, aAcc);
                MFMA32R(a0[5], f11, aAcc);
            }
        } else {
            if (t + 1 < TT) {
                MFMA32L(a0[2], &Xa[n32][32 * wv + 8 * h32], aAcc);
                MFMA32L(a0[3], &Xa[n32][32 * wv + 16 + 8 * h32], aAcc);
                MFMA32R(a0[4], f10, aAcc);
                MFMA32R(a0[5], f11, aAcc);
            }
        }
        __syncthreads();   // #4 (zz-D reads done -> safe for next ZZWR-A)

        // ---- gather h2(t) via tags -> fragments + stage Xh2; issue audio(t+2) ----
        TGATHER(f20, f21, gb2, T);
        *(u32x4*)&Xh2[n32][32 * wv + 8 * h32] = f20;
        *(u32x4*)&Xh2[n32][32 * wv + 16 + 8 * h32] = f21;
        if (wv < 4 && t + 2 < TT) {
            #pragma unroll
            for (int s = 0; s < 8; ++s)
                av[s] = a4[(size_t)(32 * g + 8 * bg + s) * 32768 + (size_t)(t + 2) * 64 + aq];
        }
        // no barrier: Xh2 readers (head) separated by sync #1/#2 of t+1
    }
    // ---- epilogue: head for t = TT-1 ----
    __syncthreads();
    if (wv < 2) HEAD_BODY(TT - 1);
    // ---- BN stats reduce (waves 0,1; lanes 0..15) ----
    if (wv < 2 && lane < 16) {
        #pragma unroll
        for (int m = 8; m >= 1; m >>= 1) {
            ys0 += __shfl_xor(ys0, m, 64); ys1 += __shfl_xor(ys1, m, 64);
            ys2 += __shfl_xor(ys2, m, 64); ys3 += __shfl_xor(ys3, m, 64);
            yq0 += __shfl_xor(yq0, m, 64); yq1 += __shfl_xor(yq1, m, 64);
            yq2 += __shfl_xor(yq2, m, 64); yq3 += __shfl_xor(yq3, m, 64);
        }
        if (lane == 0) {
            atomicAdd(&gsum[4 * w + 0], ys0); atomicAdd(&gsum[4 * w + 1], ys1);
            atomicAdd(&gsum[4 * w + 2], ys2); atomicAdd(&gsum[4 * w + 3], ys3);
            atomicAdd(&gsq[4 * w + 0], yq0); atomicAdd(&gsq[4 * w + 1], yq1);
            atomicAdd(&gsq[4 * w + 2], yq2); atomicAdd(&gsq[4 * w + 3], yq3);
        }
    }
}

// ---------------- final head: BN(train) + ReLU + Linear(128->6) ----------------
__global__ __launch_bounds__(256) void head_kernel(
    const f16* __restrict__ ybuf, const float* __restrict__ gsum, const float* __restrict__ gsq,
    const float* __restrict__ gamma, const float* __restrict__ beta,
    const float* __restrict__ W2, const float* __restrict__ b2,
    float* __restrict__ out)
{
    __shared__ float sc[NF], sh[NF], W2s[6 * NF], b2s[6];
    const int tid = threadIdx.x;
    if (tid < NF) {
        const float invN = 1.f / (float)NTOT;
        float mu = gsum[tid] * invN;
        float var = gsq[tid] * invN - mu * mu;
        float iv = rsqrtf(var + 1e-5f);
        float s = gamma[tid] * iv;
        sc[tid] = s;
        sh[tid] = beta[tid] - mu * s;
    }
    for (int i = tid; i < 6 * NF; i += 256) W2s[i] = W2[i];
    if (tid < 6) b2s[tid] = b2[tid];
    __syncthreads();

    size_t n = (size_t)blockIdx.x * 256 + tid;
    const h2_t* yr = (const h2_t*)(ybuf + n * NF);
    float a0 = b2s[0], a1 = b2s[1], a2 = b2s[2], a3 = b2s[3], a4 = b2s[4], a5 = b2s[5];
    #pragma unroll 8
    for (int p = 0; p < 64; ++p) {
        h2_t v = yr[p];
        int f0 = 2 * p, f1 = 2 * p + 1;
        float v0 = fmaxf(fmaf((float)v.x, sc[f0], sh[f0]), 0.f);
        float v1 = fmaxf(fmaf((float)v.y, sc[f1], sh[f1]), 0.f);
        a0 = fmaf(v0, W2s[0 * NF + f0], a0); a0 = fmaf(v1, W2s[0 * NF + f1], a0);
        a1 = fmaf(v0, W2s[1 * NF + f0], a1); a1 = fmaf(v1, W2s[1 * NF + f1], a1);
        a2 = fmaf(v0, W2s[2 * NF + f0], a2); a2 = fmaf(v1, W2s[2 * NF + f1], a2);
        a3 = fmaf(v0, W2s[3 * NF + f0], a3); a3 = fmaf(v1, W2s[3 * NF + f1], a3);
        a4 = fmaf(v0, W2s[4 * NF + f0], a4); a4 = fmaf(v1, W2s[4 * NF + f1], a4);
        a5 = fmaf(v0, W2s[5 * NF + f0], a5); a5 = fmaf(v1, W2s[5 * NF + f1], a5);
    }
    float* op = out + n * 6;
    op[0] = a0; op[1] = a1; op[2] = a2; op[3] = a3; op[4] = a4; op[5] = a5;
}

extern "C" void kernel_launch(void* const* d_in, const int* in_sizes, int n_in,
                              void* d_out, int out_size, void* d_ws, size_t ws_size,
                              hipStream_t stream) {
    const float* audio = (const float*)d_in[1];
    const float* s_rt  = (const float*)d_in[2];
    const float* Wih0  = (const float*)d_in[3];
    const float* Whh0  = (const float*)d_in[4];
    const float* bih0  = (const float*)d_in[5];
    const float* bhh0  = (const float*)d_in[6];
    const float* Wih1  = (const float*)d_in[7];
    const float* Whh1  = (const float*)d_in[8];
    const float* bih1  = (const float*)d_in[9];
    const float* bhh1  = (const float*)d_in[10];
    const float* W1    = (const float*)d_in[11];
    const float* b1    = (const float*)d_in[12];
    const float* gamma = (const float*)d_in[13];
    const float* beta  = (const float*)d_in[14];
    const float* W2    = (const float*)d_in[15];
    const float* b2    = (const float*)d_in[16];

    char* ws = (char*)d_ws;
    f16* WA0    = (f16*)(ws + OFF_WA0);
    f16* WA1    = (f16*)(ws + OFF_WA1);
    f16* WAH    = (f16*)(ws + OFF_WAH);
    float* gsum = (float*)(ws + OFF_GSUM);
    float* gsq  = (float*)(ws + OFF_GSQ);
    u32* gh1    = (u32*)(ws + OFF_GH1);
    u32* gh2    = (u32*)(ws + OFF_GH2);
    f16* ybuf   = (f16*)(ws + OFF_Y);
    float* out  = (float*)d_out;

    // prep: 786432 + 524288 + 131072 + 256 + 131072 = 1,573,120 = 6145 * 256
    prep_kernel<<<6145, 256, 0, stream>>>(Wih0, Whh0, Wih1, Whh1, W1,
                                          WA0, WA1, WAH, gsum, gh1);

    lstm_group_kernel<<<256, 512, 0, stream>>>(audio, s_rt,
                                               (const uint4*)WA0, (const uint4*)WA1, (const uint4*)WAH,
                                               bih0, bhh0, bih1, bhh1, b1,
                                               gh1, gh2, ybuf, gsum, gsq);

    head_kernel<<<NTOT / 256, 256, 0, stream>>>(ybuf, gsum, gsq, gamma, beta, W2, b2, out);
}